// Round 8
// baseline (2529.259 us; speedup 1.0000x reference)
//
#include <hip/hip_runtime.h>
#include <hip/hip_bf16.h>
#include <cmath>

#define B_ 16
#define S_ 2048
#define D_ 512
#define L_ 4
#define FF_ 2048
#define V_ 33

typedef unsigned short u16;
typedef __attribute__((ext_vector_type(8))) short bf16x8;
typedef __attribute__((ext_vector_type(4))) float f32x4;

__device__ __forceinline__ u16 f2bf(float f) {
    unsigned x = __float_as_uint(f);
    unsigned r = (x + 0x7fffu + ((x >> 16) & 1u)) >> 16;
    return (u16)r;
}
__device__ __forceinline__ float bf2f(u16 u) { return __uint_as_float(((unsigned)u) << 16); }

__device__ __forceinline__ float wave_sum(float v) {
#pragma unroll
    for (int o = 32; o; o >>= 1) v += __shfl_xor(v, o);
    return v;
}
__device__ __forceinline__ float wave_max(float v) {
#pragma unroll
    for (int o = 32; o; o >>= 1) v = fmaxf(v, __shfl_xor(v, o));
    return v;
}

__device__ __forceinline__ void gload16(const u16* g, u16* l) {
    __builtin_amdgcn_global_load_lds((const __attribute__((address_space(1))) void*)g,
                                     (__attribute__((address_space(3))) void*)l, 16, 0, 0);
}

__device__ __forceinline__ uint4 pack8(const u16* ov) {
    uint4 p;
    p.x = (unsigned)ov[0] | ((unsigned)ov[1] << 16);
    p.y = (unsigned)ov[2] | ((unsigned)ov[3] << 16);
    p.z = (unsigned)ov[4] | ((unsigned)ov[5] << 16);
    p.w = (unsigned)ov[6] | ((unsigned)ov[7] << 16);
    return p;
}

// ---------------- embedding ----------------
__global__ __launch_bounds__(256) void embed_kernel(
    const int* __restrict__ ids, const int* __restrict__ attr,
    const float* __restrict__ tok, const float* __restrict__ pos,
    const float* __restrict__ attre, float* __restrict__ x)
{
    int idx = blockIdx.x * 256 + threadIdx.x;          // float4 index
    const int total = B_ * S_ * (D_ / 4);
    if (idx >= total) return;
    int d4 = idx & (D_ / 4 - 1);
    int bs = idx >> 7;            // D_/4 = 128
    int s  = bs & (S_ - 1);
    int b  = bs >> 11;
    int id = ids[bs];
    int a  = attr[b];
    float4 t  = ((const float4*)tok)[id * (D_ / 4) + d4];
    float4 p  = ((const float4*)pos)[s * (D_ / 4) + d4];
    float4 at = ((const float4*)attre)[a * (D_ / 4) + d4];
    float4 o;
    o.x = t.x + p.x + at.x; o.y = t.y + p.y + at.y;
    o.z = t.z + p.z + at.z; o.w = t.w + p.w + at.w;
    ((float4*)x)[idx] = o;
}

// ---------------- layernorm (fp32 in -> bf16 out) ----------------
__global__ __launch_bounds__(256) void ln_kernel(
    const float* __restrict__ in, u16* __restrict__ out,
    const float* __restrict__ w, const float* __restrict__ b, int rows)
{
    int gw = (int)((blockIdx.x * 256 + threadIdx.x) >> 6);
    int lane = threadIdx.x & 63;
    if (gw >= rows) return;
    const float4* p = (const float4*)(in + (size_t)gw * D_);
    float4 a0 = p[lane * 2], a1 = p[lane * 2 + 1];
    float xv[8] = {a0.x, a0.y, a0.z, a0.w, a1.x, a1.y, a1.z, a1.w};
    float s = 0.f;
#pragma unroll
    for (int k = 0; k < 8; k++) s += xv[k];
    s = wave_sum(s);
    float mu = s * (1.f / D_);
    float q = 0.f;
#pragma unroll
    for (int k = 0; k < 8; k++) { float d = xv[k] - mu; q += d * d; }
    q = wave_sum(q);
    float rs = rsqrtf(q * (1.f / D_) + 1e-5f);
    const float4* w4 = (const float4*)w;
    const float4* b4 = (const float4*)b;
    float4 w0 = w4[lane * 2], w1v = w4[lane * 2 + 1];
    float4 b0 = b4[lane * 2], b1v = b4[lane * 2 + 1];
    float wv[8] = {w0.x, w0.y, w0.z, w0.w, w1v.x, w1v.y, w1v.z, w1v.w};
    float bv[8] = {b0.x, b0.y, b0.z, b0.w, b1v.x, b1v.y, b1v.z, b1v.w};
    u16 ov[8];
#pragma unroll
    for (int k = 0; k < 8; k++) ov[k] = f2bf((xv[k] - mu) * rs * wv[k] + bv[k]);
    *(uint4*)(out + (size_t)gw * D_ + lane * 8) = pack8(ov);
}

// ---------------- transpose (-> bf16) ----------------
__device__ __forceinline__ float toF(float v) { return v; }
__device__ __forceinline__ float toF(u16 v) { return bf2f(v); }

template <typename T>
__global__ void transpose_bf(const T* __restrict__ in, u16* __restrict__ out,
                             int R, int C, size_t sIn, size_t sOut)
{
    __shared__ float tile[32][33];
    const T* ip = in + (size_t)blockIdx.z * sIn;
    u16* op = out + (size_t)blockIdx.z * sOut;
    int tx = threadIdx.x, ty = threadIdx.y;
    int c = blockIdx.x * 32 + tx;
#pragma unroll
    for (int i = 0; i < 4; i++) {
        int r = blockIdx.y * 32 + ty + i * 8;
        tile[ty + i * 8][tx] = toF(ip[(size_t)r * C + c]);
    }
    __syncthreads();
#pragma unroll
    for (int i = 0; i < 4; i++) {
        int oc = blockIdx.x * 32 + ty + i * 8;
        op[(size_t)oc * R + blockIdx.y * 32 + tx] = f2bf(tile[tx][ty + i * 8]);
    }
}

// ---------------- softmax (bf16 scores, IN-PLACE -> bf16 probs) ----------------
__global__ __launch_bounds__(256) void softmax_kernel(
    u16* scP, const float* __restrict__ mask, int b0)
{
    __shared__ float red[8];
    const int row = blockIdx.x;              // chunk-local
    const int b = b0 + (row >> 11);
    u16* prow = scP + (size_t)row * S_;
    const int tid = threadIdx.x, lane = tid & 63, wid = tid >> 6;
    uint4 pk = *(const uint4*)(prow + tid * 8);
    float v[8];
    v[0] = bf2f((u16)(pk.x & 0xffff)); v[1] = bf2f((u16)(pk.x >> 16));
    v[2] = bf2f((u16)(pk.y & 0xffff)); v[3] = bf2f((u16)(pk.y >> 16));
    v[4] = bf2f((u16)(pk.z & 0xffff)); v[5] = bf2f((u16)(pk.z >> 16));
    v[6] = bf2f((u16)(pk.w & 0xffff)); v[7] = bf2f((u16)(pk.w >> 16));
    const float4* m4 = (const float4*)(mask + (size_t)b * S_);
    float4 mm0 = m4[tid * 2], mm1 = m4[tid * 2 + 1];
    float mk[8] = {mm0.x, mm0.y, mm0.z, mm0.w, mm1.x, mm1.y, mm1.z, mm1.w};
#pragma unroll
    for (int k = 0; k < 8; k++) v[k] += (1.f - mk[k]) * -1e9f;
    float mx = -1e30f;
#pragma unroll
    for (int k = 0; k < 8; k++) mx = fmaxf(mx, v[k]);
    mx = wave_max(mx);
    if (lane == 0) red[wid] = mx;
    __syncthreads();
    mx = fmaxf(fmaxf(red[0], red[1]), fmaxf(red[2], red[3]));
    float s = 0.f;
#pragma unroll
    for (int k = 0; k < 8; k++) { v[k] = __expf(v[k] - mx); s += v[k]; }
    s = wave_sum(s);
    if (lane == 0) red[4 + wid] = s;
    __syncthreads();
    s = red[4] + red[5] + red[6] + red[7];
    float inv = 1.f / s;
    u16 ov[8];
#pragma unroll
    for (int k = 0; k < 8; k++) ov[k] = f2bf(v[k] * inv);
    *(uint4*)(prow + tid * 8) = pack8(ov);
}

// ---------------- NT GEMM: C[m,n] = sum_k A[m,k]*B[n,k], bf16 in, MFMA ----------
// 128x128 tile, BK=64. T2 XOR-swizzle both-sides (rule #21); bank conflicts = 0
// (verified R5). T1: m204 bijective XCD-chunk remap (verified R7).
enum { E_SC = 0, E_PV = 1, E_GELU = 2, E_FF2 = 3 };

template <int EPI>
__global__ __launch_bounds__(256) void gemm_nt(
    const u16* __restrict__ A, size_t sAz, int lda,
    const u16* __restrict__ B, size_t sBz, int ldb,
    float* Cf, u16* Cb, size_t sCz, int ldc,
    int K, float scale,
    const float* resid, size_t sRz,
    const float* __restrict__ bias)
{
    __shared__ __align__(16) u16 ldsA[128 * 64];
    __shared__ __align__(16) u16 ldsB[128 * 64];

    // ---- T1: XCD-aware bijective tile remap (m204) ----
    const int gx = gridDim.x, gy = gridDim.y;
    const int nwg = gx * gy * gridDim.z;
    int lid = blockIdx.x + gx * (blockIdx.y + gy * blockIdx.z);
    {
        const int q = nwg >> 3, r = nwg & 7;
        const int xcd = lid & 7, idx = lid >> 3;
        lid = (xcd < r ? xcd * (q + 1) : r * (q + 1) + (xcd - r) * q) + idx;
    }
    const int bx = lid % gx;
    const int t2 = lid / gx;
    const int by = t2 % gy;
    const int z  = t2 / gy;

    A += (size_t)z * sAz;
    B += (size_t)z * sBz;
    const size_t coff = (size_t)z * sCz;
    const int brow = by * 128, bcol = bx * 128;
    const int tid = threadIdx.x, lane = tid & 63, wid = tid >> 6;
    const int wr = wid >> 1, wc = wid & 1;

    f32x4 acc[4][4];
#pragma unroll
    for (int m = 0; m < 4; m++)
#pragma unroll
        for (int n = 0; n < 4; n++) acc[m][n] = 0.0f;

    // staging: dest row = r*32 + wid*8 + (lane>>3); dest chunk = lane&7 (linear)
    const int lg   = lane >> 3;                 // == dest row & 7
    const int srow = wid * 8 + lg;              // row within a 32-row round
    const int skk  = ((lane & 7) ^ lg) << 3;    // pre-swizzled source k-offset

    const int l15 = lane & 15, l7 = lane & 7, kh = lane >> 4;  // kh 0..3

    for (int k0 = 0; k0 < K; k0 += 64) {
        __syncthreads();
#pragma unroll
        for (int r = 0; r < 4; r++) {
            const u16* ga = A + (size_t)(brow + r * 32 + srow) * lda + (k0 + skk);
            const u16* gb = B + (size_t)(bcol + r * 32 + srow) * ldb + (k0 + skk);
            gload16(ga, &ldsA[r * 2048 + wid * 512]);
            gload16(gb, &ldsB[r * 2048 + wid * 512]);
        }
        __syncthreads();
#pragma unroll
        for (int kk = 0; kk < 64; kk += 32) {
            const int kc = (kk >> 3) + kh;      // logical 16B-chunk index 0..7
            const int kswz = ((kc ^ l7) << 3);  // swizzled k elem offset
            bf16x8 af[4], bfv[4];
#pragma unroll
            for (int m = 0; m < 4; m++)
                af[m] = *(const bf16x8*)&ldsA[(wr * 64 + m * 16 + l15) * 64 + kswz];
#pragma unroll
            for (int n = 0; n < 4; n++)
                bfv[n] = *(const bf16x8*)&ldsB[(wc * 64 + n * 16 + l15) * 64 + kswz];
#pragma unroll
            for (int m = 0; m < 4; m++)
#pragma unroll
                for (int n = 0; n < 4; n++)
                    acc[m][n] = __builtin_amdgcn_mfma_f32_16x16x32_bf16(af[m], bfv[n], acc[m][n], 0, 0, 0);
        }
    }

#pragma unroll
    for (int m = 0; m < 4; m++)
#pragma unroll
        for (int n = 0; n < 4; n++) {
            int rowb = brow + wr * 64 + m * 16 + ((lane >> 4) << 2);
            int col  = bcol + wc * 64 + n * 16 + l15;
#pragma unroll
            for (int j = 0; j < 4; j++) {
                int row = rowb + j;
                float v = acc[m][n][j];
                size_t off = coff + (size_t)row * ldc + col;
                if constexpr (EPI == E_SC) {
                    Cb[off] = f2bf(v * scale);
                } else if constexpr (EPI == E_PV) {
                    Cf[off] = v + resid[(size_t)z * sRz + (size_t)row * ldc + col];
                } else if constexpr (EPI == E_GELU) {
                    float t = v + bias[col];
                    Cb[off] = f2bf(0.5f * t * (1.f + erff(t * 0.70710678118f)));
                } else {
                    Cf[off] = v + bias[col] + resid[(size_t)row * ldc + col];
                }
            }
        }
}

// ---------------- output projection: out = x @ W + b, W [512,33] ----------------
// One block per 32-row group; 4 waves = 4 row-subgroups; lane = (kc, r).
// ALL v-loops fully unrolled so acc[] stays in registers (rule #20 — the
// #pragma unroll 1 version put acc in scratch: 39MB WRITE_SIZE, 117us).
// Shared obuf[32][33] -> one contiguous 4224B (33 full lines) store per block.
#define WTS 72
__global__ __launch_bounds__(256) void outproj_kernel(
    const float* __restrict__ x, const float* __restrict__ W,
    const float* __restrict__ bias, float* __restrict__ out)
{
    __shared__ __align__(16) u16 WT[V_ * 8 * WTS];   // 38016 B
    __shared__ float obuf[32][V_ + 1];               // 4352 B
    for (int j = threadIdx.x; j < V_ * 8 * 64; j += 256) {
        int e = j & 63, t = j >> 6;
        int kc = t & 7, v = t >> 3;
        WT[(v * 8 + kc) * WTS + e] = f2bf(W[(kc * 64 + e) * V_ + v]);
    }
    __syncthreads();

    const int tid = threadIdx.x, lane = tid & 63, wid = tid >> 6;
    const int kc = lane >> 3;          // K-chunk 0..7 (64 d each)
    const int r  = lane & 7;           // row-within-subgroup 0..7
    const int row = blockIdx.x * 32 + wid * 8 + r;
    const float4* xr = (const float4*)(x + (size_t)row * D_);

    float acc[V_];
#pragma unroll
    for (int v = 0; v < V_; v++) acc[v] = 0.f;

#pragma unroll
    for (int h = 0; h < 2; h++) {
        float xv[32];
#pragma unroll
        for (int j = 0; j < 8; j++) {
            float4 t = xr[kc * 16 + h * 8 + j];
            xv[j * 4 + 0] = t.x; xv[j * 4 + 1] = t.y;
            xv[j * 4 + 2] = t.z; xv[j * 4 + 3] = t.w;
        }
#pragma unroll
        for (int v = 0; v < V_; v++) {
            const bf16x8* wr = (const bf16x8*)&WT[(v * 8 + kc) * WTS + h * 32];
            float p = 0.f;
#pragma unroll
            for (int j = 0; j < 4; j++) {
                bf16x8 wv = wr[j];
#pragma unroll
                for (int k = 0; k < 8; k++)
                    p += xv[j * 8 + k] * bf2f((u16)wv[k]);
            }
            acc[v] += p;
        }
    }
#pragma unroll
    for (int v = 0; v < V_; v++) {
        float s = acc[v];
        s += __shfl_xor(s, 8);
        s += __shfl_xor(s, 16);
        s += __shfl_xor(s, 32);
        if (kc == 0) obuf[wid * 8 + r][v] = s + bias[v];
    }
    __syncthreads();
    float* ob = out + (size_t)blockIdx.x * (32 * V_);
#pragma unroll 1
    for (int i = tid; i < 32 * V_; i += 256) {
        ob[i] = obuf[i / V_][i % V_];
    }
}

extern "C" void kernel_launch(void* const* d_in, const int* in_sizes, int n_in,
                              void* d_out, int out_size, void* d_ws, size_t ws_size,
                              hipStream_t stream)
{
    const int*   input_ids = (const int*)d_in[0];
    const int*   comb      = (const int*)d_in[1];
    const float* amask     = (const float*)d_in[2];
    const float* tok       = (const float*)d_in[3];
    const float* pos       = (const float*)d_in[4];
    const float* attre     = (const float*)d_in[5];
    const float* ln_w      = (const float*)d_in[6];
    const float* ln_b      = (const float*)d_in[7];
    const float* w1        = (const float*)d_in[8];
    const float* b1        = (const float*)d_in[9];
    const float* w2        = (const float*)d_in[10];
    const float* b2        = (const float*)d_in[11];
    const float* out_w     = (const float*)d_in[12];
    const float* out_b     = (const float*)d_in[13];
    float* out = (float*)d_out;
    (void)in_sizes; (void)n_in; (void)out_size;

    // ---- adaptive workspace tiers (ws_size-aware; deterministic) ----
    // tierF: NB_A=16, RC=32768 -> ~270 MB  (full batch; PV/FF2 at 4 blocks/CU)
    // tier0: NB_A=8,  RC=16384 -> ~169 MB  (verified working)
    int NB_A, RC;
    if      (ws_size >= 280000000ULL) { NB_A = 16; RC = 32768; }
    else if (ws_size >= 175000000ULL) { NB_A = 8;  RC = 16384; }
    else if (ws_size >= 125000000ULL) { NB_A = 4;  RC = 8192;  }
    else                              { NB_A = 2;  RC = 4096;  }
    const int HR = NB_A * S_;          // == RC for all tiers

    unsigned char* ws = (unsigned char*)d_ws;
    size_t off = 0;
    auto carve = [&](size_t bytes) {
        void* p = ws + off;
        off += (bytes + 255) & ~(size_t)255;
        return p;
    };
    float* x    = (float*)carve((size_t)B_ * S_ * D_ * 4);        // residual stream (in-place)
    u16* w1t    = (u16*)carve((size_t)D_ * FF_ * 2);              // per-layer
    u16* w2t    = (u16*)carve((size_t)D_ * FF_ * 2);              // per-layer
    u16* h      = (u16*)carve((size_t)HR * D_ * 2);               // LN output chunk
    u16* hT     = (u16*)carve((size_t)NB_A * S_ * D_ * 2);        // per-group transpose
    // union: scores/probs (attention) and FFN hidden share one region
    size_t scP_bytes  = (size_t)NB_A * S_ * S_ * 2;
    size_t tbuf_bytes = (size_t)RC * FF_ * 2;
    void* un = carve(scP_bytes > tbuf_bytes ? scP_bytes : tbuf_bytes);
    u16* scP  = (u16*)un;
    u16* tbuf = (u16*)un;

    const float scl = 1.0f / sqrtf((float)D_);
    const int nG = B_ / NB_A;              // attention groups
    const int nC = (B_ * S_) / RC;         // FFN chunks

    // embeddings
    embed_kernel<<<(B_ * S_ * (D_ / 4)) / 256, 256, 0, stream>>>(input_ids, comb, tok, pos, attre, x);

    for (int l = 0; l < L_; l++) {
        const float* lw = ln_w + l * D_;
        const float* lb = ln_b + l * D_;

        // ---- attention (per group of NB_A batches); x <- P@h + x ----
        for (int g = 0; g < nG; g++) {
            float* xg = x + (size_t)g * NB_A * S_ * D_;
            ln_kernel<<<(NB_A * S_) / 4, 256, 0, stream>>>(xg, h, lw, lb, NB_A * S_);
            transpose_bf<u16><<<dim3(D_ / 32, S_ / 32, NB_A), dim3(32, 8), 0, stream>>>(
                h, hT, S_, D_, (size_t)S_ * D_, (size_t)S_ * D_);
            // scores = h h^T * scale  -> bf16
            gemm_nt<E_SC><<<dim3(S_ / 128, S_ / 128, NB_A), 256, 0, stream>>>(
                h, (size_t)S_ * D_, D_,
                h, (size_t)S_ * D_, D_,
                nullptr, scP, (size_t)S_ * S_, S_,
                D_, scl, nullptr, 0, nullptr);
            // softmax in place (bf16 -> bf16)
            softmax_kernel<<<NB_A * S_, 256, 0, stream>>>(scP, amask, g * NB_A);
            // x[group] = P @ h + x[group]   (in place)
            gemm_nt<E_PV><<<dim3(D_ / 128, S_ / 128, NB_A), 256, 0, stream>>>(
                scP, (size_t)S_ * S_, S_,
                hT, (size_t)S_ * D_, S_,
                xg, nullptr, (size_t)S_ * D_, D_,
                S_, 1.f, xg, (size_t)S_ * D_, nullptr);
        }

        // ---- per-layer weight transposes (fp32 -> bf16, K-contiguous) ----
        transpose_bf<float><<<dim3(FF_ / 32, D_ / 32, 1), dim3(32, 8), 0, stream>>>(
            w1 + (size_t)l * D_ * FF_, w1t, D_, FF_, 0, 0);
        transpose_bf<float><<<dim3(D_ / 32, FF_ / 32, 1), dim3(32, 8), 0, stream>>>(
            w2 + (size_t)l * FF_ * D_, w2t, FF_, D_, 0, 0);

        // ---- FFN (per chunk of RC rows); x <- ffn(LN(x)) + x ----
        for (int c = 0; c < nC; c++) {
            size_t roff = (size_t)c * RC;
            ln_kernel<<<RC / 4, 256, 0, stream>>>(x + roff * D_, h, lw, lb, RC);
            gemm_nt<E_GELU><<<dim3(FF_ / 128, RC / 128, 1), 256, 0, stream>>>(
                h, 0, D_,
                w1t, 0, D_,
                nullptr, tbuf, 0, FF_,
                D_, 1.f, nullptr, 0, b1 + l * FF_);
            gemm_nt<E_FF2><<<dim3(D_ / 128, RC / 128, 1), 256, 0, stream>>>(
                tbuf, 0, FF_,
                w2t, 0, FF_,
                x + roff * D_, nullptr, 0, D_,
                FF_, 1.f, x + roff * D_, 0, b2 + l * D_);
        }
    }

    // out = x @ out_w + out_b
    outproj_kernel<<<(B_ * S_) / 32, 256, 0, stream>>>(x, out_w, out_b, out);
}

// Round 9
// 2202.926 us; speedup vs baseline: 1.1481x; 1.1481x over previous
//
#include <hip/hip_runtime.h>
#include <hip/hip_bf16.h>
#include <cmath>

#define B_ 16
#define S_ 2048
#define D_ 512
#define L_ 4
#define FF_ 2048
#define V_ 33

typedef unsigned short u16;
typedef __attribute__((ext_vector_type(8))) short bf16x8;
typedef __attribute__((ext_vector_type(4))) float f32x4;

__device__ __forceinline__ u16 f2bf(float f) {
    unsigned x = __float_as_uint(f);
    unsigned r = (x + 0x7fffu + ((x >> 16) & 1u)) >> 16;
    return (u16)r;
}
__device__ __forceinline__ float bf2f(u16 u) { return __uint_as_float(((unsigned)u) << 16); }

__device__ __forceinline__ float wave_sum(float v) {
#pragma unroll
    for (int o = 32; o; o >>= 1) v += __shfl_xor(v, o);
    return v;
}
__device__ __forceinline__ float wave_max(float v) {
#pragma unroll
    for (int o = 32; o; o >>= 1) v = fmaxf(v, __shfl_xor(v, o));
    return v;
}

__device__ __forceinline__ void gload16(const u16* g, u16* l) {
    __builtin_amdgcn_global_load_lds((const __attribute__((address_space(1))) void*)g,
                                     (__attribute__((address_space(3))) void*)l, 16, 0, 0);
}

__device__ __forceinline__ uint4 pack8(const u16* ov) {
    uint4 p;
    p.x = (unsigned)ov[0] | ((unsigned)ov[1] << 16);
    p.y = (unsigned)ov[2] | ((unsigned)ov[3] << 16);
    p.z = (unsigned)ov[4] | ((unsigned)ov[5] << 16);
    p.w = (unsigned)ov[6] | ((unsigned)ov[7] << 16);
    return p;
}

// ---------------- embedding ----------------
__global__ __launch_bounds__(256) void embed_kernel(
    const int* __restrict__ ids, const int* __restrict__ attr,
    const float* __restrict__ tok, const float* __restrict__ pos,
    const float* __restrict__ attre, float* __restrict__ x)
{
    int idx = blockIdx.x * 256 + threadIdx.x;          // float4 index
    const int total = B_ * S_ * (D_ / 4);
    if (idx >= total) return;
    int d4 = idx & (D_ / 4 - 1);
    int bs = idx >> 7;            // D_/4 = 128
    int s  = bs & (S_ - 1);
    int b  = bs >> 11;
    int id = ids[bs];
    int a  = attr[b];
    float4 t  = ((const float4*)tok)[id * (D_ / 4) + d4];
    float4 p  = ((const float4*)pos)[s * (D_ / 4) + d4];
    float4 at = ((const float4*)attre)[a * (D_ / 4) + d4];
    float4 o;
    o.x = t.x + p.x + at.x; o.y = t.y + p.y + at.y;
    o.z = t.z + p.z + at.z; o.w = t.w + p.w + at.w;
    ((float4*)x)[idx] = o;
}

// ---------------- layernorm (fp32 in -> bf16 out) ----------------
__global__ __launch_bounds__(256) void ln_kernel(
    const float* __restrict__ in, u16* __restrict__ out,
    const float* __restrict__ w, const float* __restrict__ b, int rows)
{
    int gw = (int)((blockIdx.x * 256 + threadIdx.x) >> 6);
    int lane = threadIdx.x & 63;
    if (gw >= rows) return;
    const float4* p = (const float4*)(in + (size_t)gw * D_);
    float4 a0 = p[lane * 2], a1 = p[lane * 2 + 1];
    float xv[8] = {a0.x, a0.y, a0.z, a0.w, a1.x, a1.y, a1.z, a1.w};
    float s = 0.f;
#pragma unroll
    for (int k = 0; k < 8; k++) s += xv[k];
    s = wave_sum(s);
    float mu = s * (1.f / D_);
    float q = 0.f;
#pragma unroll
    for (int k = 0; k < 8; k++) { float d = xv[k] - mu; q += d * d; }
    q = wave_sum(q);
    float rs = rsqrtf(q * (1.f / D_) + 1e-5f);
    const float4* w4 = (const float4*)w;
    const float4* b4 = (const float4*)b;
    float4 w0 = w4[lane * 2], w1v = w4[lane * 2 + 1];
    float4 b0 = b4[lane * 2], b1v = b4[lane * 2 + 1];
    float wv[8] = {w0.x, w0.y, w0.z, w0.w, w1v.x, w1v.y, w1v.z, w1v.w};
    float bv[8] = {b0.x, b0.y, b0.z, b0.w, b1v.x, b1v.y, b1v.z, b1v.w};
    u16 ov[8];
#pragma unroll
    for (int k = 0; k < 8; k++) ov[k] = f2bf((xv[k] - mu) * rs * wv[k] + bv[k]);
    *(uint4*)(out + (size_t)gw * D_ + lane * 8) = pack8(ov);
}

// ---------------- transpose (-> bf16) ----------------
__device__ __forceinline__ float toF(float v) { return v; }
__device__ __forceinline__ float toF(u16 v) { return bf2f(v); }

template <typename T>
__global__ void transpose_bf(const T* __restrict__ in, u16* __restrict__ out,
                             int R, int C, size_t sIn, size_t sOut)
{
    __shared__ float tile[32][33];
    const T* ip = in + (size_t)blockIdx.z * sIn;
    u16* op = out + (size_t)blockIdx.z * sOut;
    int tx = threadIdx.x, ty = threadIdx.y;
    int c = blockIdx.x * 32 + tx;
#pragma unroll
    for (int i = 0; i < 4; i++) {
        int r = blockIdx.y * 32 + ty + i * 8;
        tile[ty + i * 8][tx] = toF(ip[(size_t)r * C + c]);
    }
    __syncthreads();
#pragma unroll
    for (int i = 0; i < 4; i++) {
        int oc = blockIdx.x * 32 + ty + i * 8;
        op[(size_t)oc * R + blockIdx.y * 32 + tx] = f2bf(tile[tx][ty + i * 8]);
    }
}

// ---------------- softmax (bf16 scores, IN-PLACE -> bf16 probs) ----------------
__global__ __launch_bounds__(256) void softmax_kernel(
    u16* scP, const float* __restrict__ mask, int b0)
{
    __shared__ float red[8];
    const int row = blockIdx.x;              // chunk-local
    const int b = b0 + (row >> 11);
    u16* prow = scP + (size_t)row * S_;
    const int tid = threadIdx.x, lane = tid & 63, wid = tid >> 6;
    uint4 pk = *(const uint4*)(prow + tid * 8);
    float v[8];
    v[0] = bf2f((u16)(pk.x & 0xffff)); v[1] = bf2f((u16)(pk.x >> 16));
    v[2] = bf2f((u16)(pk.y & 0xffff)); v[3] = bf2f((u16)(pk.y >> 16));
    v[4] = bf2f((u16)(pk.z & 0xffff)); v[5] = bf2f((u16)(pk.z >> 16));
    v[6] = bf2f((u16)(pk.w & 0xffff)); v[7] = bf2f((u16)(pk.w >> 16));
    const float4* m4 = (const float4*)(mask + (size_t)b * S_);
    float4 mm0 = m4[tid * 2], mm1 = m4[tid * 2 + 1];
    float mk[8] = {mm0.x, mm0.y, mm0.z, mm0.w, mm1.x, mm1.y, mm1.z, mm1.w};
#pragma unroll
    for (int k = 0; k < 8; k++) v[k] += (1.f - mk[k]) * -1e9f;
    float mx = -1e30f;
#pragma unroll
    for (int k = 0; k < 8; k++) mx = fmaxf(mx, v[k]);
    mx = wave_max(mx);
    if (lane == 0) red[wid] = mx;
    __syncthreads();
    mx = fmaxf(fmaxf(red[0], red[1]), fmaxf(red[2], red[3]));
    float s = 0.f;
#pragma unroll
    for (int k = 0; k < 8; k++) { v[k] = __expf(v[k] - mx); s += v[k]; }
    s = wave_sum(s);
    if (lane == 0) red[4 + wid] = s;
    __syncthreads();
    s = red[4] + red[5] + red[6] + red[7];
    float inv = 1.f / s;
    u16 ov[8];
#pragma unroll
    for (int k = 0; k < 8; k++) ov[k] = f2bf(v[k] * inv);
    *(uint4*)(prow + tid * 8) = pack8(ov);
}

// ---------------- NT GEMM: C[m,n] = sum_k A[m,k]*B[n,k], bf16 in, MFMA ----------
// 128x128 tile, BK=64. T2 XOR-swizzle both-sides (rule #21); bank conflicts = 0
// (verified R5). T1: m204 bijective XCD-chunk remap (verified R7).
enum { E_SC = 0, E_PV = 1, E_GELU = 2, E_FF2 = 3 };

template <int EPI>
__global__ __launch_bounds__(256) void gemm_nt(
    const u16* __restrict__ A, size_t sAz, int lda,
    const u16* __restrict__ B, size_t sBz, int ldb,
    float* Cf, u16* Cb, size_t sCz, int ldc,
    int K, float scale,
    const float* resid, size_t sRz,
    const float* __restrict__ bias)
{
    __shared__ __align__(16) u16 ldsA[128 * 64];
    __shared__ __align__(16) u16 ldsB[128 * 64];

    // ---- T1: XCD-aware bijective tile remap (m204) ----
    const int gx = gridDim.x, gy = gridDim.y;
    const int nwg = gx * gy * gridDim.z;
    int lid = blockIdx.x + gx * (blockIdx.y + gy * blockIdx.z);
    {
        const int q = nwg >> 3, r = nwg & 7;
        const int xcd = lid & 7, idx = lid >> 3;
        lid = (xcd < r ? xcd * (q + 1) : r * (q + 1) + (xcd - r) * q) + idx;
    }
    const int bx = lid % gx;
    const int t2 = lid / gx;
    const int by = t2 % gy;
    const int z  = t2 / gy;

    A += (size_t)z * sAz;
    B += (size_t)z * sBz;
    const size_t coff = (size_t)z * sCz;
    const int brow = by * 128, bcol = bx * 128;
    const int tid = threadIdx.x, lane = tid & 63, wid = tid >> 6;
    const int wr = wid >> 1, wc = wid & 1;

    f32x4 acc[4][4];
#pragma unroll
    for (int m = 0; m < 4; m++)
#pragma unroll
        for (int n = 0; n < 4; n++) acc[m][n] = 0.0f;

    // staging: dest row = r*32 + wid*8 + (lane>>3); dest chunk = lane&7 (linear)
    const int lg   = lane >> 3;                 // == dest row & 7
    const int srow = wid * 8 + lg;              // row within a 32-row round
    const int skk  = ((lane & 7) ^ lg) << 3;    // pre-swizzled source k-offset

    const int l15 = lane & 15, l7 = lane & 7, kh = lane >> 4;  // kh 0..3

    for (int k0 = 0; k0 < K; k0 += 64) {
        __syncthreads();
#pragma unroll
        for (int r = 0; r < 4; r++) {
            const u16* ga = A + (size_t)(brow + r * 32 + srow) * lda + (k0 + skk);
            const u16* gb = B + (size_t)(bcol + r * 32 + srow) * ldb + (k0 + skk);
            gload16(ga, &ldsA[r * 2048 + wid * 512]);
            gload16(gb, &ldsB[r * 2048 + wid * 512]);
        }
        __syncthreads();
#pragma unroll
        for (int kk = 0; kk < 64; kk += 32) {
            const int kc = (kk >> 3) + kh;      // logical 16B-chunk index 0..7
            const int kswz = ((kc ^ l7) << 3);  // swizzled k elem offset
            bf16x8 af[4], bfv[4];
#pragma unroll
            for (int m = 0; m < 4; m++)
                af[m] = *(const bf16x8*)&ldsA[(wr * 64 + m * 16 + l15) * 64 + kswz];
#pragma unroll
            for (int n = 0; n < 4; n++)
                bfv[n] = *(const bf16x8*)&ldsB[(wc * 64 + n * 16 + l15) * 64 + kswz];
#pragma unroll
            for (int m = 0; m < 4; m++)
#pragma unroll
                for (int n = 0; n < 4; n++)
                    acc[m][n] = __builtin_amdgcn_mfma_f32_16x16x32_bf16(af[m], bfv[n], acc[m][n], 0, 0, 0);
        }
    }

#pragma unroll
    for (int m = 0; m < 4; m++)
#pragma unroll
        for (int n = 0; n < 4; n++) {
            int rowb = brow + wr * 64 + m * 16 + ((lane >> 4) << 2);
            int col  = bcol + wc * 64 + n * 16 + l15;
#pragma unroll
            for (int j = 0; j < 4; j++) {
                int row = rowb + j;
                float v = acc[m][n][j];
                size_t off = coff + (size_t)row * ldc + col;
                if constexpr (EPI == E_SC) {
                    Cb[off] = f2bf(v * scale);
                } else if constexpr (EPI == E_PV) {
                    Cf[off] = v + resid[(size_t)z * sRz + (size_t)row * ldc + col];
                } else if constexpr (EPI == E_GELU) {
                    float t = v + bias[col];
                    Cb[off] = f2bf(0.5f * t * (1.f + erff(t * 0.70710678118f)));
                } else {
                    Cf[off] = v + bias[col] + resid[(size_t)row * ldc + col];
                }
            }
        }
}

// ---------------- output projection: out = x @ W + b, W [512,33] ----------------
// One block per 32-row group; lane = (kc, r). Each thread loads its WHOLE
// 64-elem K-chunk into registers ONCE (64 VGPR), then loops v with a single
// scalar accumulator live per iteration (nothing array-indexed -> nothing to
// spill; R7 scratch-acc and R8 full-unroll both spilled: 39MB/602MB WRITE).
#define WTS 72
__global__ __launch_bounds__(256) void outproj_kernel(
    const float* __restrict__ x, const float* __restrict__ W,
    const float* __restrict__ bias, float* __restrict__ out)
{
    __shared__ __align__(16) u16 WT[V_ * 8 * WTS];   // 38016 B
    __shared__ float obuf[32][V_ + 1];               // 4352 B
    for (int j = threadIdx.x; j < V_ * 8 * 64; j += 256) {
        int e = j & 63, t = j >> 6;
        int kc = t & 7, v = t >> 3;
        WT[(v * 8 + kc) * WTS + e] = f2bf(W[(kc * 64 + e) * V_ + v]);
    }
    __syncthreads();

    const int tid = threadIdx.x, lane = tid & 63, wid = tid >> 6;
    const int kc = lane >> 3;          // K-chunk 0..7 (64 d each)
    const int r  = lane & 7;           // row-within-subgroup 0..7
    const int row = blockIdx.x * 32 + wid * 8 + r;
    const float4* xr = (const float4*)(x + (size_t)row * D_) + kc * 16;

    // load this thread's full 64-element x chunk into registers
    float xv[64];
#pragma unroll
    for (int j = 0; j < 16; j++) {
        float4 t = xr[j];
        xv[j * 4 + 0] = t.x; xv[j * 4 + 1] = t.y;
        xv[j * 4 + 2] = t.z; xv[j * 4 + 3] = t.w;
    }

#pragma unroll
    for (int v = 0; v < V_; v++) {
        const bf16x8* wr = (const bf16x8*)&WT[(v * 8 + kc) * WTS];
        float p = 0.f;
#pragma unroll
        for (int j = 0; j < 8; j++) {
            bf16x8 wv = wr[j];
#pragma unroll
            for (int k = 0; k < 8; k++)
                p += xv[j * 8 + k] * bf2f((u16)wv[k]);
        }
        p += __shfl_xor(p, 8);
        p += __shfl_xor(p, 16);
        p += __shfl_xor(p, 32);
        if (kc == 0) obuf[wid * 8 + r][v] = p + bias[v];
    }
    __syncthreads();
    float* ob = out + (size_t)blockIdx.x * (32 * V_);
#pragma unroll 1
    for (int i = tid; i < 32 * V_; i += 256) {
        ob[i] = obuf[i / V_][i % V_];
    }
}

extern "C" void kernel_launch(void* const* d_in, const int* in_sizes, int n_in,
                              void* d_out, int out_size, void* d_ws, size_t ws_size,
                              hipStream_t stream)
{
    const int*   input_ids = (const int*)d_in[0];
    const int*   comb      = (const int*)d_in[1];
    const float* amask     = (const float*)d_in[2];
    const float* tok       = (const float*)d_in[3];
    const float* pos       = (const float*)d_in[4];
    const float* attre     = (const float*)d_in[5];
    const float* ln_w      = (const float*)d_in[6];
    const float* ln_b      = (const float*)d_in[7];
    const float* w1        = (const float*)d_in[8];
    const float* b1        = (const float*)d_in[9];
    const float* w2        = (const float*)d_in[10];
    const float* b2        = (const float*)d_in[11];
    const float* out_w     = (const float*)d_in[12];
    const float* out_b     = (const float*)d_in[13];
    float* out = (float*)d_out;
    (void)in_sizes; (void)n_in; (void)out_size;

    // ---- adaptive workspace tiers (ws_size-aware; deterministic) ----
    int NB_A, RC;
    if      (ws_size >= 280000000ULL) { NB_A = 16; RC = 32768; }
    else if (ws_size >= 175000000ULL) { NB_A = 8;  RC = 16384; }
    else if (ws_size >= 125000000ULL) { NB_A = 4;  RC = 8192;  }
    else                              { NB_A = 2;  RC = 4096;  }
    const int HR = NB_A * S_;          // == RC for all tiers

    unsigned char* ws = (unsigned char*)d_ws;
    size_t off = 0;
    auto carve = [&](size_t bytes) {
        void* p = ws + off;
        off += (bytes + 255) & ~(size_t)255;
        return p;
    };
    float* x    = (float*)carve((size_t)B_ * S_ * D_ * 4);        // residual stream (in-place)
    u16* w1t    = (u16*)carve((size_t)D_ * FF_ * 2);              // per-layer
    u16* w2t    = (u16*)carve((size_t)D_ * FF_ * 2);              // per-layer
    u16* h      = (u16*)carve((size_t)HR * D_ * 2);               // LN output chunk
    u16* hT     = (u16*)carve((size_t)NB_A * S_ * D_ * 2);        // per-group transpose
    // union: scores/probs (attention) and FFN hidden share one region
    size_t scP_bytes  = (size_t)NB_A * S_ * S_ * 2;
    size_t tbuf_bytes = (size_t)RC * FF_ * 2;
    void* un = carve(scP_bytes > tbuf_bytes ? scP_bytes : tbuf_bytes);
    u16* scP  = (u16*)un;
    u16* tbuf = (u16*)un;

    const float scl = 1.0f / sqrtf((float)D_);
    const int nG = B_ / NB_A;              // attention groups
    const int nC = (B_ * S_) / RC;         // FFN chunks

    // embeddings
    embed_kernel<<<(B_ * S_ * (D_ / 4)) / 256, 256, 0, stream>>>(input_ids, comb, tok, pos, attre, x);

    for (int l = 0; l < L_; l++) {
        const float* lw = ln_w + l * D_;
        const float* lb = ln_b + l * D_;

        // ---- attention (per group of NB_A batches); x <- P@h + x ----
        for (int g = 0; g < nG; g++) {
            float* xg = x + (size_t)g * NB_A * S_ * D_;
            ln_kernel<<<(NB_A * S_) / 4, 256, 0, stream>>>(xg, h, lw, lb, NB_A * S_);
            transpose_bf<u16><<<dim3(D_ / 32, S_ / 32, NB_A), dim3(32, 8), 0, stream>>>(
                h, hT, S_, D_, (size_t)S_ * D_, (size_t)S_ * D_);
            // scores = h h^T * scale  -> bf16
            gemm_nt<E_SC><<<dim3(S_ / 128, S_ / 128, NB_A), 256, 0, stream>>>(
                h, (size_t)S_ * D_, D_,
                h, (size_t)S_ * D_, D_,
                nullptr, scP, (size_t)S_ * S_, S_,
                D_, scl, nullptr, 0, nullptr);
            // softmax in place (bf16 -> bf16)
            softmax_kernel<<<NB_A * S_, 256, 0, stream>>>(scP, amask, g * NB_A);
            // x[group] = P @ h + x[group]   (in place)
            gemm_nt<E_PV><<<dim3(D_ / 128, S_ / 128, NB_A), 256, 0, stream>>>(
                scP, (size_t)S_ * S_, S_,
                hT, (size_t)S_ * D_, S_,
                xg, nullptr, (size_t)S_ * D_, D_,
                S_, 1.f, xg, (size_t)S_ * D_, nullptr);
        }

        // ---- per-layer weight transposes (fp32 -> bf16, K-contiguous) ----
        transpose_bf<float><<<dim3(FF_ / 32, D_ / 32, 1), dim3(32, 8), 0, stream>>>(
            w1 + (size_t)l * D_ * FF_, w1t, D_, FF_, 0, 0);
        transpose_bf<float><<<dim3(D_ / 32, FF_ / 32, 1), dim3(32, 8), 0, stream>>>(
            w2 + (size_t)l * FF_ * D_, w2t, FF_, D_, 0, 0);

        // ---- FFN (per chunk of RC rows); x <- ffn(LN(x)) + x ----
        for (int c = 0; c < nC; c++) {
            size_t roff = (size_t)c * RC;
            ln_kernel<<<RC / 4, 256, 0, stream>>>(x + roff * D_, h, lw, lb, RC);
            gemm_nt<E_GELU><<<dim3(FF_ / 128, RC / 128, 1), 256, 0, stream>>>(
                h, 0, D_,
                w1t, 0, D_,
                nullptr, tbuf, 0, FF_,
                D_, 1.f, nullptr, 0, b1 + l * FF_);
            gemm_nt<E_FF2><<<dim3(D_ / 128, RC / 128, 1), 256, 0, stream>>>(
                tbuf, 0, FF_,
                w2t, 0, FF_,
                x + roff * D_, nullptr, 0, D_,
                FF_, 1.f, x + roff * D_, 0, b2 + l * D_);
        }
    }

    // out = x @ out_w + out_b
    outproj_kernel<<<(B_ * S_) / 32, 256, 0, stream>>>(x, out_w, out_b, out);
}

// Round 10
// 2178.750 us; speedup vs baseline: 1.1609x; 1.0111x over previous
//
#include <hip/hip_runtime.h>
#include <hip/hip_bf16.h>
#include <cmath>

#define B_ 16
#define S_ 2048
#define D_ 512
#define L_ 4
#define FF_ 2048
#define V_ 33

typedef unsigned short u16;
typedef __attribute__((ext_vector_type(8))) short bf16x8;
typedef __attribute__((ext_vector_type(4))) float f32x4;

__device__ __forceinline__ u16 f2bf(float f) {
    unsigned x = __float_as_uint(f);
    unsigned r = (x + 0x7fffu + ((x >> 16) & 1u)) >> 16;
    return (u16)r;
}
__device__ __forceinline__ float bf2f(u16 u) { return __uint_as_float(((unsigned)u) << 16); }

__device__ __forceinline__ float wave_sum(float v) {
#pragma unroll
    for (int o = 32; o; o >>= 1) v += __shfl_xor(v, o);
    return v;
}

__device__ __forceinline__ void gload16(const u16* g, u16* l) {
    __builtin_amdgcn_global_load_lds((const __attribute__((address_space(1))) void*)g,
                                     (__attribute__((address_space(3))) void*)l, 16, 0, 0);
}

__device__ __forceinline__ uint4 pack8(const u16* ov) {
    uint4 p;
    p.x = (unsigned)ov[0] | ((unsigned)ov[1] << 16);
    p.y = (unsigned)ov[2] | ((unsigned)ov[3] << 16);
    p.z = (unsigned)ov[4] | ((unsigned)ov[5] << 16);
    p.w = (unsigned)ov[6] | ((unsigned)ov[7] << 16);
    return p;
}

// ---------------- embedding ----------------
__global__ __launch_bounds__(256) void embed_kernel(
    const int* __restrict__ ids, const int* __restrict__ attr,
    const float* __restrict__ tok, const float* __restrict__ pos,
    const float* __restrict__ attre, float* __restrict__ x)
{
    int idx = blockIdx.x * 256 + threadIdx.x;          // float4 index
    const int total = B_ * S_ * (D_ / 4);
    if (idx >= total) return;
    int d4 = idx & (D_ / 4 - 1);
    int bs = idx >> 7;            // D_/4 = 128
    int s  = bs & (S_ - 1);
    int b  = bs >> 11;
    int id = ids[bs];
    int a  = attr[b];
    float4 t  = ((const float4*)tok)[id * (D_ / 4) + d4];
    float4 p  = ((const float4*)pos)[s * (D_ / 4) + d4];
    float4 at = ((const float4*)attre)[a * (D_ / 4) + d4];
    float4 o;
    o.x = t.x + p.x + at.x; o.y = t.y + p.y + at.y;
    o.z = t.z + p.z + at.z; o.w = t.w + p.w + at.w;
    ((float4*)x)[idx] = o;
}

// ---------------- layernorm (fp32 in -> bf16 out) ----------------
__global__ __launch_bounds__(256) void ln_kernel(
    const float* __restrict__ in, u16* __restrict__ out,
    const float* __restrict__ w, const float* __restrict__ b, int rows)
{
    int gw = (int)((blockIdx.x * 256 + threadIdx.x) >> 6);
    int lane = threadIdx.x & 63;
    if (gw >= rows) return;
    const float4* p = (const float4*)(in + (size_t)gw * D_);
    float4 a0 = p[lane * 2], a1 = p[lane * 2 + 1];
    float xv[8] = {a0.x, a0.y, a0.z, a0.w, a1.x, a1.y, a1.z, a1.w};
    float s = 0.f;
#pragma unroll
    for (int k = 0; k < 8; k++) s += xv[k];
    s = wave_sum(s);
    float mu = s * (1.f / D_);
    float q = 0.f;
#pragma unroll
    for (int k = 0; k < 8; k++) { float d = xv[k] - mu; q += d * d; }
    q = wave_sum(q);
    float rs = rsqrtf(q * (1.f / D_) + 1e-5f);
    const float4* w4 = (const float4*)w;
    const float4* b4 = (const float4*)b;
    float4 w0 = w4[lane * 2], w1v = w4[lane * 2 + 1];
    float4 b0 = b4[lane * 2], b1v = b4[lane * 2 + 1];
    float wv[8] = {w0.x, w0.y, w0.z, w0.w, w1v.x, w1v.y, w1v.z, w1v.w};
    float bv[8] = {b0.x, b0.y, b0.z, b0.w, b1v.x, b1v.y, b1v.z, b1v.w};
    u16 ov[8];
#pragma unroll
    for (int k = 0; k < 8; k++) ov[k] = f2bf((xv[k] - mu) * rs * wv[k] + bv[k]);
    *(uint4*)(out + (size_t)gw * D_ + lane * 8) = pack8(ov);
}

// ---------------- transpose (-> bf16) ----------------
__device__ __forceinline__ float toF(float v) { return v; }
__device__ __forceinline__ float toF(u16 v) { return bf2f(v); }

template <typename T>
__global__ void transpose_bf(const T* __restrict__ in, u16* __restrict__ out,
                             int R, int C, size_t sIn, size_t sOut)
{
    __shared__ float tile[32][33];
    const T* ip = in + (size_t)blockIdx.z * sIn;
    u16* op = out + (size_t)blockIdx.z * sOut;
    int tx = threadIdx.x, ty = threadIdx.y;
    int c = blockIdx.x * 32 + tx;
#pragma unroll
    for (int i = 0; i < 4; i++) {
        int r = blockIdx.y * 32 + ty + i * 8;
        tile[ty + i * 8][tx] = toF(ip[(size_t)r * C + c]);
    }
    __syncthreads();
#pragma unroll
    for (int i = 0; i < 4; i++) {
        int oc = blockIdx.x * 32 + ty + i * 8;
        op[(size_t)oc * R + blockIdx.y * 32 + tx] = f2bf(tile[tx][ty + i * 8]);
    }
}

// ---------------- row sums of expP (bf16) -> l[row]  (deterministic) ---------
__global__ __launch_bounds__(256) void rowsum_kernel(
    const u16* __restrict__ P, float* __restrict__ l, int rows)
{
    int gw = (int)((blockIdx.x * 256 + threadIdx.x) >> 6);
    int lane = threadIdx.x & 63;
    if (gw >= rows) return;
    const u16* pr = P + (size_t)gw * S_;
    float s = 0.f;
#pragma unroll
    for (int k = 0; k < 4; k++) {
        uint4 pk = *(const uint4*)(pr + k * 512 + lane * 8);
        s += bf2f((u16)(pk.x & 0xffff)) + bf2f((u16)(pk.x >> 16));
        s += bf2f((u16)(pk.y & 0xffff)) + bf2f((u16)(pk.y >> 16));
        s += bf2f((u16)(pk.z & 0xffff)) + bf2f((u16)(pk.z >> 16));
        s += bf2f((u16)(pk.w & 0xffff)) + bf2f((u16)(pk.w >> 16));
    }
    s = wave_sum(s);
    if (lane == 0) l[gw] = s;
}

// ---------------- NT GEMM: C[m,n] = sum_k A[m,k]*B[n,k], bf16 in, MFMA ----------
// 128x128 tile, BK=64. T2 XOR-swizzle both-sides (rule #21); bank conflicts = 0
// (verified R5). T1: m204 bijective XCD-chunk remap (verified R7).
// Softmax is fused: E_SC writes exp(s*scale+mask_add) (no max needed: LN bounds
// |s| <= sqrt(512) = 22.6, exp <= 6.7e9, row sum <= 1.4e13 -- fp32-safe; softmax
// is shift-invariant so this is exact). E_PV divides by the row sum l (aux).
enum { E_SC = 0, E_PV = 1, E_GELU = 2, E_FF2 = 3 };

template <int EPI>
__global__ __launch_bounds__(256) void gemm_nt(
    const u16* __restrict__ A, size_t sAz, int lda,
    const u16* __restrict__ B, size_t sBz, int ldb,
    float* Cf, u16* Cb, size_t sCz, int ldc,
    int K, float scale,
    const float* resid, size_t sRz,
    const float* __restrict__ bias,
    const float* __restrict__ aux, int b0)
{
    __shared__ __align__(16) u16 ldsA[128 * 64];
    __shared__ __align__(16) u16 ldsB[128 * 64];

    // ---- T1: XCD-aware bijective tile remap (m204) ----
    const int gx = gridDim.x, gy = gridDim.y;
    const int nwg = gx * gy * gridDim.z;
    int lid = blockIdx.x + gx * (blockIdx.y + gy * blockIdx.z);
    {
        const int q = nwg >> 3, r = nwg & 7;
        const int xcd = lid & 7, idx = lid >> 3;
        lid = (xcd < r ? xcd * (q + 1) : r * (q + 1) + (xcd - r) * q) + idx;
    }
    const int bx = lid % gx;
    const int t2 = lid / gx;
    const int by = t2 % gy;
    const int z  = t2 / gy;

    A += (size_t)z * sAz;
    B += (size_t)z * sBz;
    const size_t coff = (size_t)z * sCz;
    const int brow = by * 128, bcol = bx * 128;
    const int tid = threadIdx.x, lane = tid & 63, wid = tid >> 6;
    const int wr = wid >> 1, wc = wid & 1;

    f32x4 acc[4][4];
#pragma unroll
    for (int m = 0; m < 4; m++)
#pragma unroll
        for (int n = 0; n < 4; n++) acc[m][n] = 0.0f;

    // staging: dest row = r*32 + wid*8 + (lane>>3); dest chunk = lane&7 (linear)
    const int lg   = lane >> 3;                 // == dest row & 7
    const int srow = wid * 8 + lg;              // row within a 32-row round
    const int skk  = ((lane & 7) ^ lg) << 3;    // pre-swizzled source k-offset

    const int l15 = lane & 15, l7 = lane & 7, kh = lane >> 4;  // kh 0..3

    for (int k0 = 0; k0 < K; k0 += 64) {
        __syncthreads();
#pragma unroll
        for (int r = 0; r < 4; r++) {
            const u16* ga = A + (size_t)(brow + r * 32 + srow) * lda + (k0 + skk);
            const u16* gb = B + (size_t)(bcol + r * 32 + srow) * ldb + (k0 + skk);
            gload16(ga, &ldsA[r * 2048 + wid * 512]);
            gload16(gb, &ldsB[r * 2048 + wid * 512]);
        }
        __syncthreads();
#pragma unroll
        for (int kk = 0; kk < 64; kk += 32) {
            const int kc = (kk >> 3) + kh;      // logical 16B-chunk index 0..7
            const int kswz = ((kc ^ l7) << 3);  // swizzled k elem offset
            bf16x8 af[4], bfv[4];
#pragma unroll
            for (int m = 0; m < 4; m++)
                af[m] = *(const bf16x8*)&ldsA[(wr * 64 + m * 16 + l15) * 64 + kswz];
#pragma unroll
            for (int n = 0; n < 4; n++)
                bfv[n] = *(const bf16x8*)&ldsB[(wc * 64 + n * 16 + l15) * 64 + kswz];
#pragma unroll
            for (int m = 0; m < 4; m++)
#pragma unroll
                for (int n = 0; n < 4; n++)
                    acc[m][n] = __builtin_amdgcn_mfma_f32_16x16x32_bf16(af[m], bfv[n], acc[m][n], 0, 0, 0);
        }
    }

#pragma unroll
    for (int m = 0; m < 4; m++)
#pragma unroll
        for (int n = 0; n < 4; n++) {
            int rowb = brow + wr * 64 + m * 16 + ((lane >> 4) << 2);
            int col  = bcol + wc * 64 + n * 16 + l15;
#pragma unroll
            for (int j = 0; j < 4; j++) {
                int row = rowb + j;
                float v = acc[m][n][j];
                size_t off = coff + (size_t)row * ldc + col;
                if constexpr (EPI == E_SC) {
                    // fused masked exp (un-normalized softmax numerator)
                    float mv = aux[(size_t)(b0 + z) * S_ + col];
                    Cb[off] = f2bf(__expf(v * scale + (1.f - mv) * -1e9f));
                } else if constexpr (EPI == E_PV) {
                    float lv = aux[(size_t)z * S_ + row];
                    Cf[off] = v / lv + resid[(size_t)z * sRz + (size_t)row * ldc + col];
                } else if constexpr (EPI == E_GELU) {
                    float t = v + bias[col];
                    Cb[off] = f2bf(0.5f * t * (1.f + erff(t * 0.70710678118f)));
                } else {
                    Cf[off] = v + bias[col] + resid[(size_t)row * ldc + col];
                }
            }
        }
}

// ---------------- output projection: out = x @ W + b, W [512,33] ----------------
// One block per 32-row group; lane = (kc, r). Whole 64-elem K-chunk in regs,
// single scalar accumulator per v (verified R9: WRITE_SIZE = output size).
#define WTS 72
__global__ __launch_bounds__(256) void outproj_kernel(
    const float* __restrict__ x, const float* __restrict__ W,
    const float* __restrict__ bias, float* __restrict__ out)
{
    __shared__ __align__(16) u16 WT[V_ * 8 * WTS];   // 38016 B
    __shared__ float obuf[32][V_ + 1];               // 4352 B
    for (int j = threadIdx.x; j < V_ * 8 * 64; j += 256) {
        int e = j & 63, t = j >> 6;
        int kc = t & 7, v = t >> 3;
        WT[(v * 8 + kc) * WTS + e] = f2bf(W[(kc * 64 + e) * V_ + v]);
    }
    __syncthreads();

    const int tid = threadIdx.x, lane = tid & 63, wid = tid >> 6;
    const int kc = lane >> 3;          // K-chunk 0..7 (64 d each)
    const int r  = lane & 7;           // row-within-subgroup 0..7
    const int row = blockIdx.x * 32 + wid * 8 + r;
    const float4* xr = (const float4*)(x + (size_t)row * D_) + kc * 16;

    float xv[64];
#pragma unroll
    for (int j = 0; j < 16; j++) {
        float4 t = xr[j];
        xv[j * 4 + 0] = t.x; xv[j * 4 + 1] = t.y;
        xv[j * 4 + 2] = t.z; xv[j * 4 + 3] = t.w;
    }

#pragma unroll
    for (int v = 0; v < V_; v++) {
        const bf16x8* wr = (const bf16x8*)&WT[(v * 8 + kc) * WTS];
        float p = 0.f;
#pragma unroll
        for (int j = 0; j < 8; j++) {
            bf16x8 wv = wr[j];
#pragma unroll
            for (int k = 0; k < 8; k++)
                p += xv[j * 8 + k] * bf2f((u16)wv[k]);
        }
        p += __shfl_xor(p, 8);
        p += __shfl_xor(p, 16);
        p += __shfl_xor(p, 32);
        if (kc == 0) obuf[wid * 8 + r][v] = p + bias[v];
    }
    __syncthreads();
    float* ob = out + (size_t)blockIdx.x * (32 * V_);
#pragma unroll 1
    for (int i = tid; i < 32 * V_; i += 256) {
        ob[i] = obuf[i / V_][i % V_];
    }
}

extern "C" void kernel_launch(void* const* d_in, const int* in_sizes, int n_in,
                              void* d_out, int out_size, void* d_ws, size_t ws_size,
                              hipStream_t stream)
{
    const int*   input_ids = (const int*)d_in[0];
    const int*   comb      = (const int*)d_in[1];
    const float* amask     = (const float*)d_in[2];
    const float* tok       = (const float*)d_in[3];
    const float* pos       = (const float*)d_in[4];
    const float* attre     = (const float*)d_in[5];
    const float* ln_w      = (const float*)d_in[6];
    const float* ln_b      = (const float*)d_in[7];
    const float* w1        = (const float*)d_in[8];
    const float* b1        = (const float*)d_in[9];
    const float* w2        = (const float*)d_in[10];
    const float* b2        = (const float*)d_in[11];
    const float* out_w     = (const float*)d_in[12];
    const float* out_b     = (const float*)d_in[13];
    float* out = (float*)d_out;
    (void)in_sizes; (void)n_in; (void)out_size;

    // ---- adaptive workspace tiers (ws_size-aware; deterministic) ----
    int NB_A, RC;
    if      (ws_size >= 281000000ULL) { NB_A = 16; RC = 32768; }
    else if (ws_size >= 176000000ULL) { NB_A = 8;  RC = 16384; }
    else if (ws_size >= 126000000ULL) { NB_A = 4;  RC = 8192;  }
    else                              { NB_A = 2;  RC = 4096;  }
    const int HR = NB_A * S_;          // == RC for all tiers

    unsigned char* ws = (unsigned char*)d_ws;
    size_t off = 0;
    auto carve = [&](size_t bytes) {
        void* p = ws + off;
        off += (bytes + 255) & ~(size_t)255;
        return p;
    };
    float* x    = (float*)carve((size_t)B_ * S_ * D_ * 4);        // residual stream (in-place)
    u16* w1t    = (u16*)carve((size_t)D_ * FF_ * 2);              // per-layer
    u16* w2t    = (u16*)carve((size_t)D_ * FF_ * 2);              // per-layer
    u16* h      = (u16*)carve((size_t)HR * D_ * 2);               // LN output chunk
    u16* hT     = (u16*)carve((size_t)NB_A * S_ * D_ * 2);        // per-group transpose
    float* lsum = (float*)carve((size_t)NB_A * S_ * 4);           // softmax denominators
    // union: scores/probs (attention) and FFN hidden share one region
    size_t scP_bytes  = (size_t)NB_A * S_ * S_ * 2;
    size_t tbuf_bytes = (size_t)RC * FF_ * 2;
    void* un = carve(scP_bytes > tbuf_bytes ? scP_bytes : tbuf_bytes);
    u16* scP  = (u16*)un;
    u16* tbuf = (u16*)un;

    const float scl = 1.0f / sqrtf((float)D_);
    const int nG = B_ / NB_A;              // attention groups
    const int nC = (B_ * S_) / RC;         // FFN chunks

    // embeddings
    embed_kernel<<<(B_ * S_ * (D_ / 4)) / 256, 256, 0, stream>>>(input_ids, comb, tok, pos, attre, x);

    for (int l = 0; l < L_; l++) {
        const float* lw = ln_w + l * D_;
        const float* lb = ln_b + l * D_;

        // ---- attention (per group of NB_A batches); x <- P@h + x ----
        for (int g = 0; g < nG; g++) {
            float* xg = x + (size_t)g * NB_A * S_ * D_;
            ln_kernel<<<(NB_A * S_) / 4, 256, 0, stream>>>(xg, h, lw, lb, NB_A * S_);
            transpose_bf<u16><<<dim3(D_ / 32, S_ / 32, NB_A), dim3(32, 8), 0, stream>>>(
                h, hT, S_, D_, (size_t)S_ * D_, (size_t)S_ * D_);
            // expP = exp(h h^T * scale + mask_add)  -> bf16 (fused softmax numerator)
            gemm_nt<E_SC><<<dim3(S_ / 128, S_ / 128, NB_A), 256, 0, stream>>>(
                h, (size_t)S_ * D_, D_,
                h, (size_t)S_ * D_, D_,
                nullptr, scP, (size_t)S_ * S_, S_,
                D_, scl, nullptr, 0, nullptr, amask, g * NB_A);
            // l[row] = sum of expP row (deterministic)
            rowsum_kernel<<<(NB_A * S_) / 4, 256, 0, stream>>>(scP, lsum, NB_A * S_);
            // x[group] = (expP @ h) / l + x[group]   (in place)
            gemm_nt<E_PV><<<dim3(D_ / 128, S_ / 128, NB_A), 256, 0, stream>>>(
                scP, (size_t)S_ * S_, S_,
                hT, (size_t)S_ * D_, S_,
                xg, nullptr, (size_t)S_ * D_, D_,
                S_, 1.f, xg, (size_t)S_ * D_, nullptr, lsum, 0);
        }

        // ---- per-layer weight transposes (fp32 -> bf16, K-contiguous) ----
        transpose_bf<float><<<dim3(FF_ / 32, D_ / 32, 1), dim3(32, 8), 0, stream>>>(
            w1 + (size_t)l * D_ * FF_, w1t, D_, FF_, 0, 0);
        transpose_bf<float><<<dim3(D_ / 32, FF_ / 32, 1), dim3(32, 8), 0, stream>>>(
            w2 + (size_t)l * FF_ * D_, w2t, FF_, D_, 0, 0);

        // ---- FFN (per chunk of RC rows); x <- ffn(LN(x)) + x ----
        for (int c = 0; c < nC; c++) {
            size_t roff = (size_t)c * RC;
            ln_kernel<<<RC / 4, 256, 0, stream>>>(x + roff * D_, h, lw, lb, RC);
            gemm_nt<E_GELU><<<dim3(FF_ / 128, RC / 128, 1), 256, 0, stream>>>(
                h, 0, D_,
                w1t, 0, D_,
                nullptr, tbuf, 0, FF_,
                D_, 1.f, nullptr, 0, b1 + l * FF_, nullptr, 0);
            gemm_nt<E_FF2><<<dim3(D_ / 128, RC / 128, 1), 256, 0, stream>>>(
                tbuf, 0, FF_,
                w2t, 0, FF_,
                x + roff * D_, nullptr, 0, D_,
                FF_, 1.f, x + roff * D_, 0, b2 + l * D_, nullptr, 0);
        }
    }

    // out = x @ out_w + out_b
    outproj_kernel<<<(B_ * S_) / 32, 256, 0, stream>>>(x, out_w, out_b, out);
}

// Round 11
// 2115.302 us; speedup vs baseline: 1.1957x; 1.0300x over previous
//
#include <hip/hip_runtime.h>
#include <hip/hip_bf16.h>
#include <cmath>

#define B_ 16
#define S_ 2048
#define D_ 512
#define L_ 4
#define FF_ 2048
#define V_ 33

typedef unsigned short u16;
typedef __attribute__((ext_vector_type(8))) short bf16x8;
typedef __attribute__((ext_vector_type(4))) float f32x4;

__device__ __forceinline__ u16 f2bf(float f) {
    unsigned x = __float_as_uint(f);
    unsigned r = (x + 0x7fffu + ((x >> 16) & 1u)) >> 16;
    return (u16)r;
}
__device__ __forceinline__ float bf2f(u16 u) { return __uint_as_float(((unsigned)u) << 16); }

__device__ __forceinline__ float wave_sum(float v) {
#pragma unroll
    for (int o = 32; o; o >>= 1) v += __shfl_xor(v, o);
    return v;
}

__device__ __forceinline__ void gload16(const u16* g, u16* l) {
    __builtin_amdgcn_global_load_lds((const __attribute__((address_space(1))) void*)g,
                                     (__attribute__((address_space(3))) void*)l, 16, 0, 0);
}

__device__ __forceinline__ uint4 pack8(const u16* ov) {
    uint4 p;
    p.x = (unsigned)ov[0] | ((unsigned)ov[1] << 16);
    p.y = (unsigned)ov[2] | ((unsigned)ov[3] << 16);
    p.z = (unsigned)ov[4] | ((unsigned)ov[5] << 16);
    p.w = (unsigned)ov[6] | ((unsigned)ov[7] << 16);
    return p;
}

// ---------------- embedding ----------------
__global__ __launch_bounds__(256) void embed_kernel(
    const int* __restrict__ ids, const int* __restrict__ attr,
    const float* __restrict__ tok, const float* __restrict__ pos,
    const float* __restrict__ attre, float* __restrict__ x)
{
    int idx = blockIdx.x * 256 + threadIdx.x;          // float4 index
    const int total = B_ * S_ * (D_ / 4);
    if (idx >= total) return;
    int d4 = idx & (D_ / 4 - 1);
    int bs = idx >> 7;            // D_/4 = 128
    int s  = bs & (S_ - 1);
    int b  = bs >> 11;
    int id = ids[bs];
    int a  = attr[b];
    float4 t  = ((const float4*)tok)[id * (D_ / 4) + d4];
    float4 p  = ((const float4*)pos)[s * (D_ / 4) + d4];
    float4 at = ((const float4*)attre)[a * (D_ / 4) + d4];
    float4 o;
    o.x = t.x + p.x + at.x; o.y = t.y + p.y + at.y;
    o.z = t.z + p.z + at.z; o.w = t.w + p.w + at.w;
    ((float4*)x)[idx] = o;
}

// ---------------- layernorm (fp32 in -> bf16 out) ----------------
__global__ __launch_bounds__(256) void ln_kernel(
    const float* __restrict__ in, u16* __restrict__ out,
    const float* __restrict__ w, const float* __restrict__ b, int rows)
{
    int gw = (int)((blockIdx.x * 256 + threadIdx.x) >> 6);
    int lane = threadIdx.x & 63;
    if (gw >= rows) return;
    const float4* p = (const float4*)(in + (size_t)gw * D_);
    float4 a0 = p[lane * 2], a1 = p[lane * 2 + 1];
    float xv[8] = {a0.x, a0.y, a0.z, a0.w, a1.x, a1.y, a1.z, a1.w};
    float s = 0.f;
#pragma unroll
    for (int k = 0; k < 8; k++) s += xv[k];
    s = wave_sum(s);
    float mu = s * (1.f / D_);
    float q = 0.f;
#pragma unroll
    for (int k = 0; k < 8; k++) { float d = xv[k] - mu; q += d * d; }
    q = wave_sum(q);
    float rs = rsqrtf(q * (1.f / D_) + 1e-5f);
    const float4* w4 = (const float4*)w;
    const float4* b4 = (const float4*)b;
    float4 w0 = w4[lane * 2], w1v = w4[lane * 2 + 1];
    float4 b0 = b4[lane * 2], b1v = b4[lane * 2 + 1];
    float wv[8] = {w0.x, w0.y, w0.z, w0.w, w1v.x, w1v.y, w1v.z, w1v.w};
    float bv[8] = {b0.x, b0.y, b0.z, b0.w, b1v.x, b1v.y, b1v.z, b1v.w};
    u16 ov[8];
#pragma unroll
    for (int k = 0; k < 8; k++) ov[k] = f2bf((xv[k] - mu) * rs * wv[k] + bv[k]);
    *(uint4*)(out + (size_t)gw * D_ + lane * 8) = pack8(ov);
}

// ---------------- transpose (-> bf16) ----------------
__device__ __forceinline__ float toF(float v) { return v; }
__device__ __forceinline__ float toF(u16 v) { return bf2f(v); }

template <typename T>
__global__ void transpose_bf(const T* __restrict__ in, u16* __restrict__ out,
                             int R, int C, size_t sIn, size_t sOut)
{
    __shared__ float tile[32][33];
    const T* ip = in + (size_t)blockIdx.z * sIn;
    u16* op = out + (size_t)blockIdx.z * sOut;
    int tx = threadIdx.x, ty = threadIdx.y;
    int c = blockIdx.x * 32 + tx;
#pragma unroll
    for (int i = 0; i < 4; i++) {
        int r = blockIdx.y * 32 + ty + i * 8;
        tile[ty + i * 8][tx] = toF(ip[(size_t)r * C + c]);
    }
    __syncthreads();
#pragma unroll
    for (int i = 0; i < 4; i++) {
        int oc = blockIdx.x * 32 + ty + i * 8;
        op[(size_t)oc * R + blockIdx.y * 32 + tx] = f2bf(tile[tx][ty + i * 8]);
    }
}

// ---------------- reduce 32 row-partials -> lsum[row] (deterministic) -------
__global__ __launch_bounds__(256) void rowred_kernel(
    const float* __restrict__ psum, float* __restrict__ lsum, int rows)
{
    int row = blockIdx.x * 256 + threadIdx.x;
    if (row >= rows) return;
    float s = 0.f;
#pragma unroll
    for (int i = 0; i < 32; i++) s += psum[(size_t)i * rows + row];
    lsum[row] = s;
}

// ---------------- NT GEMM: C[m,n] = sum_k A[m,k]*B[n,k], bf16 in, MFMA ----------
// 128x128 tile, BK=64. T2 XOR-swizzle both-sides (rule #21); bank conflicts = 0
// (verified R5). T1: m204 bijective XCD-chunk remap (verified R7).
// E_SC: writes exp(s*scale+mask_add) (shift-free softmax numerator; LN bounds
// |s|<=22.6 -> exp<=6.7e9, row sum<=1.4e13, fp32-safe) AND per-block row-partial
// sums into psum[colblk][row] (reduced by rowred_kernel). E_PV divides by lsum.
enum { E_SC = 0, E_PV = 1, E_GELU = 2, E_FF2 = 3 };

template <int EPI>
__global__ __launch_bounds__(256) void gemm_nt(
    const u16* __restrict__ A, size_t sAz, int lda,
    const u16* __restrict__ B, size_t sBz, int ldb,
    float* Cf, u16* Cb, size_t sCz, int ldc,
    int K, float scale,
    const float* resid, size_t sRz,
    const float* __restrict__ bias,
    const float* __restrict__ aux, int b0,
    float* __restrict__ psum)
{
    __shared__ __align__(16) u16 ldsA[128 * 64];
    __shared__ __align__(16) u16 ldsB[128 * 64];

    // ---- T1: XCD-aware bijective tile remap (m204) ----
    const int gx = gridDim.x, gy = gridDim.y;
    const int nwg = gx * gy * gridDim.z;
    int lid = blockIdx.x + gx * (blockIdx.y + gy * blockIdx.z);
    {
        const int q = nwg >> 3, r = nwg & 7;
        const int xcd = lid & 7, idx = lid >> 3;
        lid = (xcd < r ? xcd * (q + 1) : r * (q + 1) + (xcd - r) * q) + idx;
    }
    const int bx = lid % gx;
    const int t2 = lid / gx;
    const int by = t2 % gy;
    const int z  = t2 / gy;

    A += (size_t)z * sAz;
    B += (size_t)z * sBz;
    const size_t coff = (size_t)z * sCz;
    const int brow = by * 128, bcol = bx * 128;
    const int tid = threadIdx.x, lane = tid & 63, wid = tid >> 6;
    const int wr = wid >> 1, wc = wid & 1;

    f32x4 acc[4][4];
#pragma unroll
    for (int m = 0; m < 4; m++)
#pragma unroll
        for (int n = 0; n < 4; n++) acc[m][n] = 0.0f;

    // staging: dest row = r*32 + wid*8 + (lane>>3); dest chunk = lane&7 (linear)
    const int lg   = lane >> 3;                 // == dest row & 7
    const int srow = wid * 8 + lg;              // row within a 32-row round
    const int skk  = ((lane & 7) ^ lg) << 3;    // pre-swizzled source k-offset

    const int l15 = lane & 15, l7 = lane & 7, kh = lane >> 4;  // kh 0..3

    for (int k0 = 0; k0 < K; k0 += 64) {
        __syncthreads();
#pragma unroll
        for (int r = 0; r < 4; r++) {
            const u16* ga = A + (size_t)(brow + r * 32 + srow) * lda + (k0 + skk);
            const u16* gb = B + (size_t)(bcol + r * 32 + srow) * ldb + (k0 + skk);
            gload16(ga, &ldsA[r * 2048 + wid * 512]);
            gload16(gb, &ldsB[r * 2048 + wid * 512]);
        }
        __syncthreads();
#pragma unroll
        for (int kk = 0; kk < 64; kk += 32) {
            const int kc = (kk >> 3) + kh;      // logical 16B-chunk index 0..7
            const int kswz = ((kc ^ l7) << 3);  // swizzled k elem offset
            bf16x8 af[4], bfv[4];
#pragma unroll
            for (int m = 0; m < 4; m++)
                af[m] = *(const bf16x8*)&ldsA[(wr * 64 + m * 16 + l15) * 64 + kswz];
#pragma unroll
            for (int n = 0; n < 4; n++)
                bfv[n] = *(const bf16x8*)&ldsB[(wc * 64 + n * 16 + l15) * 64 + kswz];
#pragma unroll
            for (int m = 0; m < 4; m++)
#pragma unroll
                for (int n = 0; n < 4; n++)
                    acc[m][n] = __builtin_amdgcn_mfma_f32_16x16x32_bf16(af[m], bfv[n], acc[m][n], 0, 0, 0);
        }
    }

    float rsum[4][4];
#pragma unroll
    for (int m = 0; m < 4; m++)
#pragma unroll
        for (int j = 0; j < 4; j++) rsum[m][j] = 0.f;

#pragma unroll
    for (int m = 0; m < 4; m++)
#pragma unroll
        for (int n = 0; n < 4; n++) {
            int rowb = brow + wr * 64 + m * 16 + ((lane >> 4) << 2);
            int col  = bcol + wc * 64 + n * 16 + l15;
#pragma unroll
            for (int j = 0; j < 4; j++) {
                int row = rowb + j;
                float v = acc[m][n][j];
                size_t off = coff + (size_t)row * ldc + col;
                if constexpr (EPI == E_SC) {
                    float mv = aux[(size_t)(b0 + z) * S_ + col];
                    float ev = __expf(v * scale + (1.f - mv) * -1e9f);
                    Cb[off] = f2bf(ev);
                    rsum[m][j] += ev;
                } else if constexpr (EPI == E_PV) {
                    float lv = aux[(size_t)z * S_ + row];
                    Cf[off] = v / lv + resid[(size_t)z * sRz + (size_t)row * ldc + col];
                } else if constexpr (EPI == E_GELU) {
                    float t = v + bias[col];
                    Cb[off] = f2bf(0.5f * t * (1.f + erff(t * 0.70710678118f)));
                } else {
                    Cf[off] = v + bias[col] + resid[(size_t)row * ldc + col];
                }
            }
        }

    if constexpr (EPI == E_SC) {
        // per-block row partial sums: reduce over the 16-lane col group, then
        // write psum[(bx*2+wc)][z*S_+row]. xor 1/2/4/8 stays within l15 group.
        const int nrows = gridDim.z * S_;
#pragma unroll
        for (int m = 0; m < 4; m++) {
            int rowl = brow + wr * 64 + m * 16 + ((lane >> 4) << 2);
#pragma unroll
            for (int j = 0; j < 4; j++) {
                float s = rsum[m][j];
                s += __shfl_xor(s, 1);
                s += __shfl_xor(s, 2);
                s += __shfl_xor(s, 4);
                s += __shfl_xor(s, 8);
                if (l15 == 0)
                    psum[(size_t)(bx * 2 + wc) * nrows + (size_t)z * S_ + rowl + j] = s;
            }
        }
    }
}

// ---------------- out_w pad+transpose: WTb[64][512] bf16 ----------------
__global__ __launch_bounds__(256) void wtb_kernel(
    const float* __restrict__ W, u16* __restrict__ WTb)
{
    int i = blockIdx.x * 256 + threadIdx.x;   // over 64*512
    if (i >= 64 * 512) return;
    int n = i >> 9, k = i & 511;
    WTb[i] = f2bf(n < V_ ? W[k * V_ + n] : 0.f);
}

// ---------------- output projection via MFMA: out = x @ W + b ----------------
// 128x64 tile, K=512. A = x (fp32) reg-staged with convert + swizzled ds_write
// (reg path allows swizzled dest; rule #21 satisfied: write-swz == read-swz).
// B = WTb (bf16, K-contig) via gload16 w/ pre-swizzled source. Epilogue stages
// the 128x33 block in LDS then stores contiguously (no partial-line sharing).
__global__ __launch_bounds__(256) void outproj_mfma(
    const float* __restrict__ x, const u16* __restrict__ WTb,
    const float* __restrict__ bias, float* __restrict__ out)
{
    __shared__ __align__(16) u16 ldsA[128 * 64];
    __shared__ __align__(16) u16 ldsB[64 * 64];
    __shared__ float obuf[128][34];
    const int brow = blockIdx.x * 128;
    const int tid = threadIdx.x, lane = tid & 63, wid = tid >> 6;
    const int wr = wid >> 1, wc = wid & 1;
    const int l15 = lane & 15, l7 = lane & 7, kh = lane >> 4;
    const int lg = lane >> 3, srow = wid * 8 + lg;
    const int skk = ((lane & 7) ^ lg) << 3;
    const int ar = tid >> 1, ah = (tid & 1) * 32;   // A staging: row, k-half

    f32x4 acc[4][2];
#pragma unroll
    for (int m = 0; m < 4; m++)
#pragma unroll
        for (int n = 0; n < 2; n++) acc[m][n] = 0.0f;

    for (int k0 = 0; k0 < 512; k0 += 64) {
        __syncthreads();
        // B: 2 staging rounds (64 rows x 64 k)
#pragma unroll
        for (int r = 0; r < 2; r++)
            gload16(WTb + (size_t)(r * 32 + srow) * 512 + (k0 + skk),
                    &ldsB[r * 2048 + wid * 512]);
        // A: 32 fp32 per thread -> bf16 -> swizzled ds_write_b128 x4
        const float4* xs = (const float4*)(x + (size_t)(brow + ar) * 512 + k0 + ah);
#pragma unroll
        for (int j = 0; j < 4; j++) {
            float4 a = xs[j * 2], b = xs[j * 2 + 1];
            u16 t[8] = {f2bf(a.x), f2bf(a.y), f2bf(a.z), f2bf(a.w),
                        f2bf(b.x), f2bf(b.y), f2bf(b.z), f2bf(b.w)};
            int kc = (ah >> 3) + j;                       // logical chunk 0..7
            *(uint4*)&ldsA[ar * 64 + ((kc ^ (ar & 7)) << 3)] = pack8(t);
        }
        __syncthreads();
#pragma unroll
        for (int kk = 0; kk < 64; kk += 32) {
            const int kc = (kk >> 3) + kh;
            const int kswz = ((kc ^ l7) << 3);
            bf16x8 af[4], bfv[2];
#pragma unroll
            for (int m = 0; m < 4; m++)
                af[m] = *(const bf16x8*)&ldsA[(wr * 64 + m * 16 + l15) * 64 + kswz];
#pragma unroll
            for (int n = 0; n < 2; n++)
                bfv[n] = *(const bf16x8*)&ldsB[(wc * 32 + n * 16 + l15) * 64 + kswz];
#pragma unroll
            for (int m = 0; m < 4; m++)
#pragma unroll
                for (int n = 0; n < 2; n++)
                    acc[m][n] = __builtin_amdgcn_mfma_f32_16x16x32_bf16(af[m], bfv[n], acc[m][n], 0, 0, 0);
        }
    }

#pragma unroll
    for (int m = 0; m < 4; m++)
#pragma unroll
        for (int n = 0; n < 2; n++) {
            int rowl = wr * 64 + m * 16 + ((lane >> 4) << 2);
            int col  = wc * 32 + n * 16 + l15;
            if (col < V_) {
#pragma unroll
                for (int j = 0; j < 4; j++)
                    obuf[rowl + j][col] = acc[m][n][j] + bias[col];
            }
        }
    __syncthreads();
    float* ob = out + (size_t)brow * V_;
#pragma unroll 1
    for (int i = tid; i < 128 * V_; i += 256)
        ob[i] = obuf[i / V_][i % V_];
}

extern "C" void kernel_launch(void* const* d_in, const int* in_sizes, int n_in,
                              void* d_out, int out_size, void* d_ws, size_t ws_size,
                              hipStream_t stream)
{
    const int*   input_ids = (const int*)d_in[0];
    const int*   comb      = (const int*)d_in[1];
    const float* amask     = (const float*)d_in[2];
    const float* tok       = (const float*)d_in[3];
    const float* pos       = (const float*)d_in[4];
    const float* attre     = (const float*)d_in[5];
    const float* ln_w      = (const float*)d_in[6];
    const float* ln_b      = (const float*)d_in[7];
    const float* w1        = (const float*)d_in[8];
    const float* b1        = (const float*)d_in[9];
    const float* w2        = (const float*)d_in[10];
    const float* b2        = (const float*)d_in[11];
    const float* out_w     = (const float*)d_in[12];
    const float* out_b     = (const float*)d_in[13];
    float* out = (float*)d_out;
    (void)in_sizes; (void)n_in; (void)out_size;

    // ---- adaptive workspace tiers (ws_size-aware; deterministic) ----
    // tierF: NB_A=16, RC=32768 -> ~323 MB ; tier0: NB_A=8 -> ~204 MB ;
    // tier1: NB_A=4 -> ~145 MB ; tier2: NB_A=2 -> ~114 MB
    int NB_A, RC;
    if      (ws_size >= 335000000ULL) { NB_A = 16; RC = 32768; }
    else if (ws_size >= 215000000ULL) { NB_A = 8;  RC = 16384; }
    else if (ws_size >= 152000000ULL) { NB_A = 4;  RC = 8192;  }
    else                              { NB_A = 2;  RC = 4096;  }
    const int HR = NB_A * S_;          // == RC for all tiers

    unsigned char* ws = (unsigned char*)d_ws;
    size_t off = 0;
    auto carve = [&](size_t bytes) {
        void* p = ws + off;
        off += (bytes + 255) & ~(size_t)255;
        return p;
    };
    float* x    = (float*)carve((size_t)B_ * S_ * D_ * 4);        // residual stream
    u16* w1t    = (u16*)carve((size_t)L_ * D_ * FF_ * 2);         // all layers
    u16* w2t    = (u16*)carve((size_t)L_ * D_ * FF_ * 2);         // all layers
    u16* h      = (u16*)carve((size_t)HR * D_ * 2);               // LN output chunk
    u16* hT     = (u16*)carve((size_t)NB_A * S_ * D_ * 2);        // per-group transpose
    float* lsum = (float*)carve((size_t)NB_A * S_ * 4);           // softmax denominators
    float* psum = (float*)carve((size_t)NB_A * S_ * 32 * 4);      // row partials
    u16* WTb    = (u16*)carve((size_t)64 * 512 * 2);              // padded out_w^T
    // union: scores/probs (attention) and FFN hidden share one region
    size_t scP_bytes  = (size_t)NB_A * S_ * S_ * 2;
    size_t tbuf_bytes = (size_t)RC * FF_ * 2;
    void* un = carve(scP_bytes > tbuf_bytes ? scP_bytes : tbuf_bytes);
    u16* scP  = (u16*)un;
    u16* tbuf = (u16*)un;

    const float scl = 1.0f / sqrtf((float)D_);
    const int nG = B_ / NB_A;              // attention groups
    const int nC = (B_ * S_) / RC;         // FFN chunks

    // embeddings + one-time weight prep (all layers batched)
    embed_kernel<<<(B_ * S_ * (D_ / 4)) / 256, 256, 0, stream>>>(input_ids, comb, tok, pos, attre, x);
    transpose_bf<float><<<dim3(FF_ / 32, D_ / 32, L_), dim3(32, 8), 0, stream>>>(
        w1, w1t, D_, FF_, (size_t)D_ * FF_, (size_t)FF_ * D_);
    transpose_bf<float><<<dim3(D_ / 32, FF_ / 32, L_), dim3(32, 8), 0, stream>>>(
        w2, w2t, FF_, D_, (size_t)FF_ * D_, (size_t)D_ * FF_);
    wtb_kernel<<<128, 256, 0, stream>>>(out_w, WTb);

    for (int l = 0; l < L_; l++) {
        const float* lw = ln_w + l * D_;
        const float* lb = ln_b + l * D_;

        // ---- attention (per group of NB_A batches); x <- P@h + x ----
        for (int g = 0; g < nG; g++) {
            float* xg = x + (size_t)g * NB_A * S_ * D_;
            ln_kernel<<<(NB_A * S_) / 4, 256, 0, stream>>>(xg, h, lw, lb, NB_A * S_);
            transpose_bf<u16><<<dim3(D_ / 32, S_ / 32, NB_A), dim3(32, 8), 0, stream>>>(
                h, hT, S_, D_, (size_t)S_ * D_, (size_t)S_ * D_);
            // expP = exp(h h^T * scale + mask_add) -> bf16, + row partial sums
            gemm_nt<E_SC><<<dim3(S_ / 128, S_ / 128, NB_A), 256, 0, stream>>>(
                h, (size_t)S_ * D_, D_,
                h, (size_t)S_ * D_, D_,
                nullptr, scP, (size_t)S_ * S_, S_,
                D_, scl, nullptr, 0, nullptr, amask, g * NB_A, psum);
            // lsum[row] = sum of 32 partials (deterministic)
            rowred_kernel<<<(NB_A * S_ + 255) / 256, 256, 0, stream>>>(psum, lsum, NB_A * S_);
            // x[group] = (expP @ h) / lsum + x[group]   (in place)
            gemm_nt<E_PV><<<dim3(D_ / 128, S_ / 128, NB_A), 256, 0, stream>>>(
                scP, (size_t)S_ * S_, S_,
                hT, (size_t)S_ * D_, S_,
                xg, nullptr, (size_t)S_ * D_, D_,
                S_, 1.f, xg, (size_t)S_ * D_, nullptr, lsum, 0, nullptr);
        }

        // ---- FFN (per chunk of RC rows); x <- ffn(LN(x)) + x ----
        for (int c = 0; c < nC; c++) {
            size_t roff = (size_t)c * RC;
            ln_kernel<<<RC / 4, 256, 0, stream>>>(x + roff * D_, h, lw, lb, RC);
            gemm_nt<E_GELU><<<dim3(FF_ / 128, RC / 128, 1), 256, 0, stream>>>(
                h, 0, D_,
                w1t + (size_t)l * FF_ * D_, 0, D_,
                nullptr, tbuf, 0, FF_,
                D_, 1.f, nullptr, 0, b1 + l * FF_, nullptr, 0, nullptr);
            gemm_nt<E_FF2><<<dim3(D_ / 128, RC / 128, 1), 256, 0, stream>>>(
                tbuf, 0, FF_,
                w2t + (size_t)l * D_ * FF_, 0, FF_,
                x + roff * D_, nullptr, 0, D_,
                FF_, 1.f, x + roff * D_, 0, b2 + l * D_, nullptr, 0, nullptr);
        }
    }

    // out = x @ out_w + out_b  (MFMA)
    outproj_mfma<<<(B_ * S_) / 128, 256, 0, stream>>>(x, WTb, out_b, out);
}